// Round 1
// baseline (84.909 us; speedup 1.0000x reference)
//
#include <hip/hip_runtime.h>
#include <cstdint>

#define BDIM 4
#define NDIM 2048
#define FDIM 64
#define CDIM 64
#define LDIM 3
#define KTOT (NDIM * LDIM) /* 6144 */

#define BM 32
#define BK 128
#define NCH (KTOT / BK) /* 48 */

typedef __attribute__((ext_vector_type(4))) float f32x4;
typedef __attribute__((ext_vector_type(8))) short s16x8;
typedef __attribute__((ext_vector_type(4))) short s16x4;

__device__ __forceinline__ unsigned short f2bf(float x) {
  union { float f; uint32_t u; } v; v.f = x;
  uint32_t r = v.u + 0x7FFFu + ((v.u >> 16) & 1u);
  return (unsigned short)(r >> 16);
}

// ---------------------------------------------------------------------------
// K1: S[b,i,c] = sum_f h0[c,f] V[b,i,f]   (fp32, ws)
//     Ut[b,c,k] = sum_f h_{1+l}[c,f] V[b,j,f], k = j*3+l   (bf16, ws)
// One wave per (j-tile of 16, edge-type le, batch).
// MFMA 16x16x32: A lane: row=l&15, k=(l>>4)*8+e ; B lane: col=l&15, same k;
// D lane: col=l&15, row=(l>>4)*4+reg.
// ---------------------------------------------------------------------------
__global__ __launch_bounds__(64) void k1_precompute(
    const float* __restrict__ V, const float* __restrict__ hw,
    float* __restrict__ S, unsigned short* __restrict__ Ut) {
  const int j0 = blockIdx.x * 16;
  const int le = blockIdx.y;  // 0 = self term, 1..3 = edge types
  const int b  = blockIdx.z;
  const int lane = threadIdx.x;
  const int q = lane & 15, g = lane >> 4;

  const float* vrow = V + ((size_t)(b * NDIM + j0 + q)) * FDIM + g * 8;
  f32x4 va0 = *(const f32x4*)(vrow);
  f32x4 va1 = *(const f32x4*)(vrow + 4);
  f32x4 va2 = *(const f32x4*)(vrow + 32);
  f32x4 va3 = *(const f32x4*)(vrow + 36);
  s16x8 a0, a1;
#pragma unroll
  for (int e = 0; e < 4; ++e) {
    a0[e]     = (short)f2bf(va0[e]);
    a0[e + 4] = (short)f2bf(va1[e]);
    a1[e]     = (short)f2bf(va2[e]);
    a1[e + 4] = (short)f2bf(va3[e]);
  }

  const float* hbase = hw + (size_t)le * CDIM * FDIM;
#pragma unroll
  for (int ct = 0; ct < 4; ++ct) {
    const float* hrow = hbase + (size_t)(ct * 16 + q) * FDIM + g * 8;
    f32x4 hb0 = *(const f32x4*)(hrow);
    f32x4 hb1 = *(const f32x4*)(hrow + 4);
    f32x4 hb2 = *(const f32x4*)(hrow + 32);
    f32x4 hb3 = *(const f32x4*)(hrow + 36);
    s16x8 b0, b1;
#pragma unroll
    for (int e = 0; e < 4; ++e) {
      b0[e]     = (short)f2bf(hb0[e]);
      b0[e + 4] = (short)f2bf(hb1[e]);
      b1[e]     = (short)f2bf(hb2[e]);
      b1[e + 4] = (short)f2bf(hb3[e]);
    }
    f32x4 acc = {0.f, 0.f, 0.f, 0.f};
    acc = __builtin_amdgcn_mfma_f32_16x16x32_bf16(a0, b0, acc, 0, 0, 0);
    acc = __builtin_amdgcn_mfma_f32_16x16x32_bf16(a1, b1, acc, 0, 0, 0);
    // D: row j = j0 + g*4 + rr, col c = ct*16 + q
    if (le == 0) {
#pragma unroll
      for (int rr = 0; rr < 4; ++rr) {
        int j = j0 + g * 4 + rr;
        S[((size_t)b * NDIM + j) * CDIM + ct * 16 + q] = acc[rr];
      }
    } else {
#pragma unroll
      for (int rr = 0; rr < 4; ++rr) {
        int j = j0 + g * 4 + rr;
        Ut[((size_t)b * CDIM + ct * 16 + q) * KTOT + (size_t)j * LDIM + (le - 1)] =
            f2bf(acc[rr]);
      }
    }
  }
}

// ---------------------------------------------------------------------------
// K2: out[b, i0..i0+31, 0..63] = relu(S + A[b] @ U[b])
// 256 threads = 4 waves: wave (wr,wc) owns rows wr*16..+15, cols wc*32..+31.
// A staged fp32->bf16 into double-buffered, XOR-swizzled LDS.
// B-fragments straight from global Ut (L2-resident, 3 MB total).
// ---------------------------------------------------------------------------
__global__ __launch_bounds__(256) void k2_main(
    const float* __restrict__ A, const unsigned short* __restrict__ Ut,
    const float* __restrict__ S, float* __restrict__ out) {
  __shared__ unsigned short Albuf[2][BM * BK];  // 2 x 8 KB

  const int b  = blockIdx.y;
  const int i0 = blockIdx.x * BM;
  const int tid  = threadIdx.x;
  const int lane = tid & 63, wid = tid >> 6;
  const int q = lane & 15, g = lane >> 4;
  const int wr = wid >> 1, wc = wid & 1;

  const float* Ab = A + ((size_t)b * NDIM + i0) * KTOT;
  const unsigned short* Utb = Ut + (size_t)b * CDIM * KTOT;

  f32x4 acc[2] = {{0.f, 0.f, 0.f, 0.f}, {0.f, 0.f, 0.f, 0.f}};
  f32x4 pv[4];

  const int r_st  = (tid >> 5);        // +8 per iteration
  const int kc_st = (tid & 31) * 4;

  // prologue: stage chunk 0 into buffer 0
#pragma unroll
  for (int it = 0; it < 4; ++it) {
    int r = it * 8 + r_st;
    pv[it] = *(const f32x4*)(Ab + (size_t)r * KTOT + kc_st);
  }
#pragma unroll
  for (int it = 0; it < 4; ++it) {
    int r = it * 8 + r_st;
    s16x4 w;
#pragma unroll
    for (int e = 0; e < 4; ++e) w[e] = (short)f2bf(pv[it][e]);
    int byteoff = r * (BK * 2) + ((kc_st * 2) ^ ((r & 7) << 4));
    *(s16x4*)((char*)(&Albuf[0][0]) + byteoff) = w;
  }
  __syncthreads();

  for (int ch = 0; ch < NCH; ++ch) {
    const int cur = ch & 1;
    // issue next chunk's A loads early (latency hides under MFMA + B loads)
    if (ch + 1 < NCH) {
#pragma unroll
      for (int it = 0; it < 4; ++it) {
        int r = it * 8 + r_st;
        pv[it] = *(const f32x4*)(Ab + (size_t)r * KTOT + (ch + 1) * BK + kc_st);
      }
    }
    // compute on current buffer
    const char* Abase = (const char*)(&Albuf[cur][0]);
    const int row = wr * 16 + q;
    const int swz = (row & 7) << 4;
#pragma unroll
    for (int kk4 = 0; kk4 < 4; ++kk4) {
      int kbyte = (kk4 * 32 + g * 8) * 2;
      s16x8 af = *(const s16x8*)(Abase + row * (BK * 2) + (kbyte ^ swz));
#pragma unroll
      for (int ct = 0; ct < 2; ++ct) {
        int c = wc * 32 + ct * 16 + q;
        s16x8 bf = *(const s16x8*)(Utb + (size_t)c * KTOT + ch * BK + kk4 * 32 + g * 8);
        acc[ct] = __builtin_amdgcn_mfma_f32_16x16x32_bf16(af, bf, acc[ct], 0, 0, 0);
      }
    }
    // write staged chunk into the other buffer
    if (ch + 1 < NCH) {
#pragma unroll
      for (int it = 0; it < 4; ++it) {
        int r = it * 8 + r_st;
        s16x4 w;
#pragma unroll
        for (int e = 0; e < 4; ++e) w[e] = (short)f2bf(pv[it][e]);
        int byteoff = r * (BK * 2) + ((kc_st * 2) ^ ((r & 7) << 4));
        *(s16x4*)((char*)(&Albuf[cur ^ 1][0]) + byteoff) = w;
      }
    }
    __syncthreads();
  }

  // epilogue: add self term, relu, store
#pragma unroll
  for (int ct = 0; ct < 2; ++ct) {
    int c = wc * 32 + ct * 16 + q;
#pragma unroll
    for (int rr = 0; rr < 4; ++rr) {
      int i = i0 + wr * 16 + g * 4 + rr;
      size_t idx = ((size_t)b * NDIM + i) * CDIM + c;
      float v = acc[ct][rr] + S[idx];
      out[idx] = v > 0.f ? v : 0.f;
    }
  }
}

extern "C" void kernel_launch(void* const* d_in, const int* in_sizes, int n_in,
                              void* d_out, int out_size, void* d_ws, size_t ws_size,
                              hipStream_t stream) {
  const float* V  = (const float*)d_in[0];
  const float* A  = (const float*)d_in[1];
  const float* hw = (const float*)d_in[2];
  float* out = (float*)d_out;

  // workspace: S (fp32, 2 MB) then Ut (bf16, 3 MB)
  float* S = (float*)d_ws;
  unsigned short* Ut =
      (unsigned short*)((char*)d_ws + (size_t)BDIM * NDIM * CDIM * sizeof(float));

  k1_precompute<<<dim3(NDIM / 16, LDIM + 1, BDIM), 64, 0, stream>>>(V, hw, S, Ut);
  k2_main<<<dim3(NDIM / BM, BDIM), 256, 0, stream>>>(A, Ut, S, out);
}

// Round 2
// 81.458 us; speedup vs baseline: 1.0424x; 1.0424x over previous
//
#include <hip/hip_runtime.h>
#include <cstdint>

#define BDIM 4
#define NDIM 2048
#define FDIM 64
#define CDIM 64
#define LDIM 3
#define KTOT (NDIM * LDIM) /* 6144 */

#define NWAVE 8                 /* waves per block = K-split factor */
#define KSEG (KTOT / NWAVE)     /* 768 */
#define KITER (KSEG / 32)       /* 24 */

typedef __attribute__((ext_vector_type(4))) float f32x4;
typedef __attribute__((ext_vector_type(2))) float f32x2;
typedef __attribute__((ext_vector_type(8))) short s16x8;

__device__ __forceinline__ unsigned short f2bf(float x) {
  union { float f; uint32_t u; } v; v.f = x;
  uint32_t r = v.u + 0x7FFFu + ((v.u >> 16) & 1u);
  return (unsigned short)(r >> 16);
}

// ---------------------------------------------------------------------------
// K1: S[b,i,c] = sum_f h0[c,f] V[b,i,f]   (fp32, ws)
//     Ut[b,c,k] = sum_f h_{1+l}[c,f] V[b,j,f], k = j*3+l   (bf16, ws)
// MFMA 16x16x32 lane maps (verified end-to-end in R1, absmax 0.5):
//   A: row=l&15, k=(l>>4)*8+e ; B: col=l&15, same k ; D: col=l&15, row=(l>>4)*4+rr
// ---------------------------------------------------------------------------
__global__ __launch_bounds__(64) void k1_precompute(
    const float* __restrict__ V, const float* __restrict__ hw,
    float* __restrict__ S, unsigned short* __restrict__ Ut) {
  const int j0 = blockIdx.x * 16;
  const int le = blockIdx.y;  // 0 = self term, 1..3 = edge types
  const int b  = blockIdx.z;
  const int lane = threadIdx.x;
  const int q = lane & 15, g = lane >> 4;

  const float* vrow = V + ((size_t)(b * NDIM + j0 + q)) * FDIM + g * 8;
  f32x4 va0 = *(const f32x4*)(vrow);
  f32x4 va1 = *(const f32x4*)(vrow + 4);
  f32x4 va2 = *(const f32x4*)(vrow + 32);
  f32x4 va3 = *(const f32x4*)(vrow + 36);
  s16x8 a0, a1;
#pragma unroll
  for (int e = 0; e < 4; ++e) {
    a0[e]     = (short)f2bf(va0[e]);
    a0[e + 4] = (short)f2bf(va1[e]);
    a1[e]     = (short)f2bf(va2[e]);
    a1[e + 4] = (short)f2bf(va3[e]);
  }

  const float* hbase = hw + (size_t)le * CDIM * FDIM;
#pragma unroll
  for (int ct = 0; ct < 4; ++ct) {
    const float* hrow = hbase + (size_t)(ct * 16 + q) * FDIM + g * 8;
    f32x4 hb0 = *(const f32x4*)(hrow);
    f32x4 hb1 = *(const f32x4*)(hrow + 4);
    f32x4 hb2 = *(const f32x4*)(hrow + 32);
    f32x4 hb3 = *(const f32x4*)(hrow + 36);
    s16x8 b0, b1;
#pragma unroll
    for (int e = 0; e < 4; ++e) {
      b0[e]     = (short)f2bf(hb0[e]);
      b0[e + 4] = (short)f2bf(hb1[e]);
      b1[e]     = (short)f2bf(hb2[e]);
      b1[e + 4] = (short)f2bf(hb3[e]);
    }
    f32x4 acc = {0.f, 0.f, 0.f, 0.f};
    acc = __builtin_amdgcn_mfma_f32_16x16x32_bf16(a0, b0, acc, 0, 0, 0);
    acc = __builtin_amdgcn_mfma_f32_16x16x32_bf16(a1, b1, acc, 0, 0, 0);
    if (le == 0) {
#pragma unroll
      for (int rr = 0; rr < 4; ++rr) {
        int j = j0 + g * 4 + rr;
        S[((size_t)b * NDIM + j) * CDIM + ct * 16 + q] = acc[rr];
      }
    } else {
#pragma unroll
      for (int rr = 0; rr < 4; ++rr) {
        int j = j0 + g * 4 + rr;
        Ut[((size_t)b * CDIM + ct * 16 + q) * KTOT + (size_t)j * LDIM + (le - 1)] =
            f2bf(acc[rr]);
      }
    }
  }
}

// ---------------------------------------------------------------------------
// K2: out[b, i0..i0+15, :] = relu(S + A[b,i0:i0+16,:] @ U[b])
// 512 threads = 8 waves. Each wave: full 16x64 output tile, K-slice of 768.
// A loaded straight to registers (no LDS, no barriers in the main loop),
// cvt fp32->bf16 in-reg, MFMA. B-fragments from L2-resident Ut.
// One LDS tree-reduce (8 partials) + self-term + relu at the end.
// ---------------------------------------------------------------------------
__global__ __launch_bounds__(512) void k2_main(
    const float* __restrict__ A, const unsigned short* __restrict__ Ut,
    const float* __restrict__ S, float* __restrict__ out) {
  __shared__ float red[NWAVE][16][64];  // 32 KB

  const int b  = blockIdx.y;
  const int i0 = blockIdx.x * 16;
  const int tid  = threadIdx.x;
  const int lane = tid & 63, w = tid >> 6;
  const int q = lane & 15, g = lane >> 4;

  const int kbase = w * KSEG;
  const float* Ap =
      A + ((size_t)(b * NDIM + i0 + q)) * KTOT + kbase + g * 8;
  const unsigned short* Up =
      Ut + ((size_t)b * CDIM + q) * KTOT + kbase + g * 8;

  f32x4 acc[4] = {{0.f,0.f,0.f,0.f},{0.f,0.f,0.f,0.f},
                  {0.f,0.f,0.f,0.f},{0.f,0.f,0.f,0.f}};

  // register-prefetched stream: A for step ks+1 issued before MFMAs of ks
  f32x4 a0 = *(const f32x4*)(Ap);
  f32x4 a1 = *(const f32x4*)(Ap + 4);
#pragma unroll 2
  for (int ks = 0; ks < KITER; ++ks) {
    f32x4 n0, n1;
    if (ks + 1 < KITER) {
      n0 = *(const f32x4*)(Ap + 32);
      n1 = *(const f32x4*)(Ap + 36);
    }
    s16x8 af;
#pragma unroll
    for (int e = 0; e < 4; ++e) {
      af[e]     = (short)f2bf(a0[e]);
      af[e + 4] = (short)f2bf(a1[e]);
    }
#pragma unroll
    for (int ct = 0; ct < 4; ++ct) {
      s16x8 bfr = *(const s16x8*)(Up + (size_t)ct * 16 * KTOT);
      acc[ct] = __builtin_amdgcn_mfma_f32_16x16x32_bf16(af, bfr, acc[ct], 0, 0, 0);
    }
    a0 = n0; a1 = n1;
    Ap += 32; Up += 32;
  }

  // partials -> LDS
#pragma unroll
  for (int ct = 0; ct < 4; ++ct)
#pragma unroll
    for (int rr = 0; rr < 4; ++rr)
      red[w][g * 4 + rr][ct * 16 + q] = acc[ct][rr];
  __syncthreads();

  // 512 threads reduce 16x64 outputs, 2 floats each
  const int r  = tid >> 5;
  const int c2 = (tid & 31) * 2;
  f32x2 s = *(const f32x2*)(&red[0][r][c2]);
#pragma unroll
  for (int ww = 1; ww < NWAVE; ++ww)
    s += *(const f32x2*)(&red[ww][r][c2]);
  size_t idx = ((size_t)(b * NDIM) + i0 + r) * CDIM + c2;
  f32x2 sv = *(const f32x2*)(S + idx);
  float v0 = s[0] + sv[0], v1 = s[1] + sv[1];
  f32x2 o;
  o[0] = v0 > 0.f ? v0 : 0.f;
  o[1] = v1 > 0.f ? v1 : 0.f;
  *(f32x2*)(out + idx) = o;
}

extern "C" void kernel_launch(void* const* d_in, const int* in_sizes, int n_in,
                              void* d_out, int out_size, void* d_ws, size_t ws_size,
                              hipStream_t stream) {
  const float* V  = (const float*)d_in[0];
  const float* A  = (const float*)d_in[1];
  const float* hw = (const float*)d_in[2];
  float* out = (float*)d_out;

  // workspace: S (fp32, 2 MB) then Ut (bf16, 3 MB)
  float* S = (float*)d_ws;
  unsigned short* Ut =
      (unsigned short*)((char*)d_ws + (size_t)BDIM * NDIM * CDIM * sizeof(float));

  k1_precompute<<<dim3(NDIM / 16, LDIM + 1, BDIM), 64, 0, stream>>>(V, hw, S, Ut);
  k2_main<<<dim3(NDIM / 16, BDIM), 512, 0, stream>>>(A, Ut, S, out);
}

// Round 4
// 65.821 us; speedup vs baseline: 1.2900x; 1.2376x over previous
//
#include <hip/hip_runtime.h>
#include <cstdint>

#define BDIM 4
#define NDIM 2048
#define FDIM 64
#define CDIM 64
#define LDIM 3
#define KTOT (NDIM * LDIM) /* 6144 */
#define NSTEP (KTOT / 32)  /* 192 */

typedef __attribute__((ext_vector_type(4))) float f32x4;
typedef __attribute__((ext_vector_type(8))) short s16x8;
typedef __attribute__((ext_vector_type(4))) unsigned int u32x4;

__device__ __forceinline__ unsigned short f2bf(float x) {
  union { float f; uint32_t u; } v; v.f = x;
  uint32_t r = v.u + 0x7FFFu + ((v.u >> 16) & 1u);
  return (unsigned short)(r >> 16);
}

__device__ __forceinline__ uint32_t cvtpk(float lo, float hi) {
  uint32_t r;
  asm("v_cvt_pk_bf16_f32 %0, %1, %2" : "=v"(r) : "v"(lo), "v"(hi));
  return r;
}

// ---------------------------------------------------------------------------
// K1: S[b,i,c] = sum_f h0[c,f] V[b,i,f]   (fp32, ws)
//     Ut[b,c,k] = sum_f h_{1+l}[c,f] V[b,j,f], k = j*3+l   (bf16, ws)
// MFMA 16x16x32 lane maps (verified R1/R2, absmax 0.5):
//   A: row=l&15, k=(l>>4)*8+e ; B: col=l&15, same k ; D: col=l&15, row=(l>>4)*4+rr
// ---------------------------------------------------------------------------
__global__ __launch_bounds__(64) void k1_precompute(
    const float* __restrict__ V, const float* __restrict__ hw,
    float* __restrict__ S, unsigned short* __restrict__ Ut) {
  const int j0 = blockIdx.x * 16;
  const int le = blockIdx.y;
  const int b  = blockIdx.z;
  const int lane = threadIdx.x;
  const int q = lane & 15, g = lane >> 4;

  const float* vrow = V + ((size_t)(b * NDIM + j0 + q)) * FDIM + g * 8;
  f32x4 va0 = *(const f32x4*)(vrow);
  f32x4 va1 = *(const f32x4*)(vrow + 4);
  f32x4 va2 = *(const f32x4*)(vrow + 32);
  f32x4 va3 = *(const f32x4*)(vrow + 36);
  s16x8 a0, a1;
#pragma unroll
  for (int e = 0; e < 4; ++e) {
    a0[e]     = (short)f2bf(va0[e]);
    a0[e + 4] = (short)f2bf(va1[e]);
    a1[e]     = (short)f2bf(va2[e]);
    a1[e + 4] = (short)f2bf(va3[e]);
  }

  const float* hbase = hw + (size_t)le * CDIM * FDIM;
#pragma unroll
  for (int ct = 0; ct < 4; ++ct) {
    const float* hrow = hbase + (size_t)(ct * 16 + q) * FDIM + g * 8;
    f32x4 hb0 = *(const f32x4*)(hrow);
    f32x4 hb1 = *(const f32x4*)(hrow + 4);
    f32x4 hb2 = *(const f32x4*)(hrow + 32);
    f32x4 hb3 = *(const f32x4*)(hrow + 36);
    s16x8 b0, b1;
#pragma unroll
    for (int e = 0; e < 4; ++e) {
      b0[e]     = (short)f2bf(hb0[e]);
      b0[e + 4] = (short)f2bf(hb1[e]);
      b1[e]     = (short)f2bf(hb2[e]);
      b1[e + 4] = (short)f2bf(hb3[e]);
    }
    f32x4 acc = {0.f, 0.f, 0.f, 0.f};
    acc = __builtin_amdgcn_mfma_f32_16x16x32_bf16(a0, b0, acc, 0, 0, 0);
    acc = __builtin_amdgcn_mfma_f32_16x16x32_bf16(a1, b1, acc, 0, 0, 0);
    if (le == 0) {
#pragma unroll
      for (int rr = 0; rr < 4; ++rr) {
        int j = j0 + g * 4 + rr;
        S[((size_t)b * NDIM + j) * CDIM + ct * 16 + q] = acc[rr];
      }
    } else {
#pragma unroll
      for (int rr = 0; rr < 4; ++rr) {
        int j = j0 + g * 4 + rr;
        Ut[((size_t)b * CDIM + ct * 16 + q) * KTOT + (size_t)j * LDIM + (le - 1)] =
            f2bf(acc[rr]);
      }
    }
  }
}

// ---------------------------------------------------------------------------
// K2: out[b, i0..i0+31, :] = relu(S + A[b,i0:i0+32,:] @ U[b])
// 4 waves, M=32, C=64 (wave w owns cols w*16..+15), full K=6144, 192 steps.
// A: global_load_lds ring (8 slots x 4KB), issue-ahead 6, manual vmcnt(4).
//    Per-lane global src pre-swizzled (chunk ^= row&7), linear LDS dest,
//    same XOR applied on the ds_read side (involution, rule #21).
// B: NORMAL C++ loads (compiler-tracked waits), 2-step prefetch, 3-reg ring.
//    vmcnt(4) invariant robust to intra-region reorder: >=6 GLLs issued after
//    A(s), >=4 vmem ops after B(s) => both retired at every step's wait.
// One raw s_barrier per step; NEVER vmcnt(0) in the loop.
// ---------------------------------------------------------------------------
__global__ __launch_bounds__(256) void k2_main(
    const float* __restrict__ A, const unsigned short* __restrict__ Ut,
    const float* __restrict__ S, float* __restrict__ out) {
  __shared__ float Abuf[8][1024];  // 8 slots x 32 rows x 32 floats = 32 KB

  const int b  = blockIdx.y;
  const int i0 = blockIdx.x * 32;
  const int tid  = threadIdx.x;
  const int lane = tid & 63, w = tid >> 6;
  const int q = lane & 15, g = lane >> 4, q7 = q & 7;

  // A global source: row = 8w + (lane>>3); 16B chunk pre-swizzled by row&7
  const int arow = 8 * w + (lane >> 3);
  const int achk = (lane & 7) ^ ((lane >> 3) & 7);
  const float* agp = A + ((size_t)(b * NDIM + i0 + arow)) * KTOT + achk * 4;

  // B global source: col c = w*16+q, k-slice g*8 (16B = 8 bf16)
  const unsigned short* bgp =
      Ut + ((size_t)(b * CDIM + w * 16 + q)) * KTOT + (size_t)g * 8;

  // LDS dest: lane-linear, wave w -> rows 8w..8w+7 of the slot
  float* ldsdst = &Abuf[0][0] + w * 256 + lane * 4;

#define GLL(slot)                                                             \
  __builtin_amdgcn_global_load_lds(                                           \
      (__attribute__((address_space(1))) void*)(agp),                         \
      (__attribute__((address_space(3))) void*)(ldsdst + (slot) * 1024),      \
      16, 0, 0)

  f32x4 acc0 = {0.f, 0.f, 0.f, 0.f}, acc1 = {0.f, 0.f, 0.f, 0.f};
  s16x8 b0, b1, b2;

  // prologue: A0..A4, B0, A5, B1 (exact order irrelevant, membership is)
  GLL(0); agp += 32;
  GLL(1); agp += 32;
  GLL(2); agp += 32;
  GLL(3); agp += 32;
  GLL(4); agp += 32;
  b0 = *(const s16x8*)(bgp); bgp += 32;
  GLL(5); agp += 32;
  b1 = *(const s16x8*)(bgp); bgp += 32;

  int s = 0;
  // step s issues {GLL A(s+6), load B(s+2)}; vmcnt(4) leaves at most the two
  // most recent regions' 4 vmem ops outstanding => A(s) in LDS, B(s) in regs.
  // GLL at step s writes slot (s-2)&7 whose readers finished before the
  // previous barrier => single barrier per step is race-free.
#define K2STEP(BW, BR)                                                        \
  do {                                                                        \
    GLL((s + 6) & 7);                                                         \
    agp += (s + 6 < NSTEP - 1) ? 32 : 0; /* tail: re-read step 191 (unused) */\
    BW = *(const s16x8*)(bgp);                                                \
    bgp += (s + 2 < NSTEP - 1) ? 32 : 0;                                      \
    asm volatile("s_waitcnt vmcnt(4)" ::: "memory");                          \
    __builtin_amdgcn_sched_barrier(0);                                        \
    __builtin_amdgcn_s_barrier();                                             \
    __builtin_amdgcn_sched_barrier(0);                                        \
    const float* sb = &Abuf[s & 7][0];                                        \
    f32x4 a00 = *(const f32x4*)(sb + q * 32 + (((2 * g) ^ q7) << 2));         \
    f32x4 a01 = *(const f32x4*)(sb + q * 32 + (((2 * g + 1) ^ q7) << 2));     \
    f32x4 a10 = *(const f32x4*)(sb + (q + 16) * 32 + (((2 * g) ^ q7) << 2));  \
    f32x4 a11 = *(const f32x4*)(sb + (q + 16) * 32 + (((2 * g + 1) ^ q7) << 2)); \
    u32x4 w0, w1;                                                             \
    w0[0] = cvtpk(a00[0], a00[1]); w0[1] = cvtpk(a00[2], a00[3]);             \
    w0[2] = cvtpk(a01[0], a01[1]); w0[3] = cvtpk(a01[2], a01[3]);             \
    w1[0] = cvtpk(a10[0], a10[1]); w1[1] = cvtpk(a10[2], a10[3]);             \
    w1[2] = cvtpk(a11[0], a11[1]); w1[3] = cvtpk(a11[2], a11[3]);             \
    acc0 = __builtin_amdgcn_mfma_f32_16x16x32_bf16(                           \
        __builtin_bit_cast(s16x8, w0), BR, acc0, 0, 0, 0);                    \
    acc1 = __builtin_amdgcn_mfma_f32_16x16x32_bf16(                           \
        __builtin_bit_cast(s16x8, w1), BR, acc1, 0, 0, 0);                    \
    ++s;                                                                      \
  } while (0)

  for (int it = 0; it < NSTEP / 3; ++it) {
    K2STEP(b2, b0);  // read B(s), prefetch B(s+2)
    K2STEP(b0, b1);
    K2STEP(b1, b2);
  }
#undef K2STEP
#undef GLL

  // drain overrun glls before s_endpgm
  asm volatile("s_waitcnt vmcnt(0)" ::: "memory");

  // epilogue: add self-term, relu, direct store
  const int c = w * 16 + q;
#pragma unroll
  for (int t = 0; t < 2; ++t) {
    f32x4 av = t ? acc1 : acc0;
#pragma unroll
    for (int rr = 0; rr < 4; ++rr) {
      int i = i0 + t * 16 + g * 4 + rr;
      size_t idx = ((size_t)(b * NDIM) + i) * CDIM + c;
      float v = av[rr] + S[idx];
      out[idx] = v > 0.f ? v : 0.f;
    }
  }
}

extern "C" void kernel_launch(void* const* d_in, const int* in_sizes, int n_in,
                              void* d_out, int out_size, void* d_ws, size_t ws_size,
                              hipStream_t stream) {
  const float* V  = (const float*)d_in[0];
  const float* A  = (const float*)d_in[1];
  const float* hw = (const float*)d_in[2];
  float* out = (float*)d_out;

  float* S = (float*)d_ws;
  unsigned short* Ut =
      (unsigned short*)((char*)d_ws + (size_t)BDIM * NDIM * CDIM * sizeof(float));

  k1_precompute<<<dim3(NDIM / 16, LDIM + 1, BDIM), 64, 0, stream>>>(V, hw, S, Ut);
  k2_main<<<dim3(NDIM / 32, BDIM), 256, 0, stream>>>(A, Ut, S, out);
}

// Round 5
// 65.661 us; speedup vs baseline: 1.2931x; 1.0024x over previous
//
#include <hip/hip_runtime.h>
#include <cstdint>

#define BDIM 4
#define NDIM 2048
#define FDIM 64
#define CDIM 64
#define LDIM 3
#define KTOT (NDIM * LDIM) /* 6144 */
#define NSTEP (KTOT / 64)  /* 96 steps of BK=64 */

typedef __attribute__((ext_vector_type(4))) float f32x4;
typedef __attribute__((ext_vector_type(8))) short s16x8;
typedef __attribute__((ext_vector_type(4))) unsigned int u32x4;

__device__ __forceinline__ unsigned short f2bf(float x) {
  union { float f; uint32_t u; } v; v.f = x;
  uint32_t r = v.u + 0x7FFFu + ((v.u >> 16) & 1u);
  return (unsigned short)(r >> 16);
}

__device__ __forceinline__ uint32_t cvtpk(float lo, float hi) {
  uint32_t r;
  asm("v_cvt_pk_bf16_f32 %0, %1, %2" : "=v"(r) : "v"(lo), "v"(hi));
  return r;
}

// ---------------------------------------------------------------------------
// K1: S[b,i,c] = sum_f h0[c,f] V[b,i,f]   (fp32, ws)
//     Ut[b,c,k] = sum_f h_{1+l}[c,f] V[b,j,f], k = j*3+l   (bf16, ws)
// MFMA 16x16x32 lane maps (verified R1/R2/R4, absmax 0.5):
//   A: row=l&15, k=(l>>4)*8+e ; B: col=l&15, same k ; D: col=l&15, row=(l>>4)*4+rr
// ---------------------------------------------------------------------------
__global__ __launch_bounds__(64) void k1_precompute(
    const float* __restrict__ V, const float* __restrict__ hw,
    float* __restrict__ S, unsigned short* __restrict__ Ut) {
  const int j0 = blockIdx.x * 16;
  const int le = blockIdx.y;
  const int b  = blockIdx.z;
  const int lane = threadIdx.x;
  const int q = lane & 15, g = lane >> 4;

  const float* vrow = V + ((size_t)(b * NDIM + j0 + q)) * FDIM + g * 8;
  f32x4 va0 = *(const f32x4*)(vrow);
  f32x4 va1 = *(const f32x4*)(vrow + 4);
  f32x4 va2 = *(const f32x4*)(vrow + 32);
  f32x4 va3 = *(const f32x4*)(vrow + 36);
  s16x8 a0, a1;
#pragma unroll
  for (int e = 0; e < 4; ++e) {
    a0[e]     = (short)f2bf(va0[e]);
    a0[e + 4] = (short)f2bf(va1[e]);
    a1[e]     = (short)f2bf(va2[e]);
    a1[e + 4] = (short)f2bf(va3[e]);
  }

  const float* hbase = hw + (size_t)le * CDIM * FDIM;
#pragma unroll
  for (int ct = 0; ct < 4; ++ct) {
    const float* hrow = hbase + (size_t)(ct * 16 + q) * FDIM + g * 8;
    f32x4 hb0 = *(const f32x4*)(hrow);
    f32x4 hb1 = *(const f32x4*)(hrow + 4);
    f32x4 hb2 = *(const f32x4*)(hrow + 32);
    f32x4 hb3 = *(const f32x4*)(hrow + 36);
    s16x8 b0, b1;
#pragma unroll
    for (int e = 0; e < 4; ++e) {
      b0[e]     = (short)f2bf(hb0[e]);
      b0[e + 4] = (short)f2bf(hb1[e]);
      b1[e]     = (short)f2bf(hb2[e]);
      b1[e + 4] = (short)f2bf(hb3[e]);
    }
    f32x4 acc = {0.f, 0.f, 0.f, 0.f};
    acc = __builtin_amdgcn_mfma_f32_16x16x32_bf16(a0, b0, acc, 0, 0, 0);
    acc = __builtin_amdgcn_mfma_f32_16x16x32_bf16(a1, b1, acc, 0, 0, 0);
    if (le == 0) {
#pragma unroll
      for (int rr = 0; rr < 4; ++rr) {
        int j = j0 + g * 4 + rr;
        S[((size_t)b * NDIM + j) * CDIM + ct * 16 + q] = acc[rr];
      }
    } else {
#pragma unroll
      for (int rr = 0; rr < 4; ++rr) {
        int j = j0 + g * 4 + rr;
        Ut[((size_t)b * CDIM + ct * 16 + q) * KTOT + (size_t)j * LDIM + (le - 1)] =
            f2bf(acc[rr]);
      }
    }
  }
}

// ---------------------------------------------------------------------------
// K2: out[b, i0..i0+15, :] = relu(S + A[b,i0:i0+16,:] @ U[b])
// M=16, BK=64/step, 96 steps, 4 waves (wave w -> cols w*16..+15), full K.
// Grid 512 = 2 blocks/CU (8 waves/CU): cross-block TLP hides ds_read/VALU/
// barrier latencies the R4 1-block/CU version exposed serially.
// A: global_load_lds ring (8 slots x 4KB), issue-ahead 6, manual vmcnt(6)
//    (3 vmem/step: 1 GLL + 2 B loads -> 6 newer ops guarantee step-s ops
//    retired). Source granule pre-swizzled tau(r,c)=r*16+(c^r); same XOR on
//    the ds_read side (involution, rule #21); octets of lanes hit 8 distinct
//    bank-quads -> conflict-free b128 reads.
// B: normal C++ loads (compiler-tracked), 2-step prefetch, 3-pair reg ring.
// One raw s_barrier per step; NEVER vmcnt(0) in the loop.
// ---------------------------------------------------------------------------
__global__ __launch_bounds__(256) void k2_main(
    const float* __restrict__ A, const unsigned short* __restrict__ Ut,
    const float* __restrict__ S, float* __restrict__ out) {
  __shared__ float Abuf[8][1024];  // 8 slots x (16 rows x 64 floats) = 32 KB

  // XCD-chunked swizzle (512 % 8 == 0): XCD x gets a contiguous tile range
  const int bid = blockIdx.x;
  const int swz = (bid & 7) * 64 + (bid >> 3);
  const int b    = swz >> 7;          // 4 batches x 128 tiles
  const int i0   = (swz & 127) * 16;
  const int tid  = threadIdx.x;
  const int lane = tid & 63, w = tid >> 6;
  const int q = lane & 15, g = lane >> 4;

  // A global source: thread t stages row r=t>>4, swizzled 16B-granule (t&15)^r
  const int arow = tid >> 4;
  const int achk = (tid & 15) ^ arow;
  const float* agp = A + ((size_t)(b * NDIM + i0 + arow)) * KTOT + achk * 4;

  // B global source: col c = w*16+q, two 16B k-slices per step (kk=0,1)
  const unsigned short* bgp =
      Ut + ((size_t)(b * CDIM + w * 16 + q)) * KTOT + (size_t)g * 8;

  // LDS dest: lane-linear within wave (GLL requirement)
  float* ldsdst = &Abuf[0][0] + w * 256 + lane * 4;

#define GLL(slot)                                                             \
  __builtin_amdgcn_global_load_lds(                                           \
      (__attribute__((address_space(1))) void*)(agp),                         \
      (__attribute__((address_space(3))) void*)(ldsdst + (slot) * 1024),      \
      16, 0, 0)

  f32x4 acc = {0.f, 0.f, 0.f, 0.f};
  s16x8 b0l, b0h, b1l, b1h, b2l, b2h;

  // prologue: slots 0..5, B pairs for steps 0,1
  GLL(0); agp += 64;
  GLL(1); agp += 64;
  GLL(2); agp += 64;
  GLL(3); agp += 64;
  GLL(4); agp += 64;
  b0l = *(const s16x8*)(bgp); b0h = *(const s16x8*)(bgp + 32); bgp += 64;
  GLL(5); agp += 64;
  b1l = *(const s16x8*)(bgp); b1h = *(const s16x8*)(bgp + 32); bgp += 64;

  int s = 0;
  // step s issues {GLL A(s+6), B pair (s+2)}; vmcnt(6) leaves at most the 6
  // ops of steps s-1,s outstanding => A(s) in LDS, B(s) pair in regs.
  // GLL at step s writes slot (s-2)&7: its readers (step s-2) completed
  // their ds_reads before passing barrier s-1, which precedes this issue.
#define K2STEP(BWl, BWh, BRl, BRh)                                            \
  do {                                                                        \
    GLL((s + 6) & 7);                                                         \
    agp += (s + 6 < NSTEP - 1) ? 64 : 0; /* tail: re-read last step */        \
    BWl = *(const s16x8*)(bgp);                                               \
    BWh = *(const s16x8*)(bgp + 32);                                          \
    bgp += (s + 2 < NSTEP - 1) ? 64 : 0;                                      \
    asm volatile("s_waitcnt vmcnt(6)" ::: "memory");                          \
    __builtin_amdgcn_sched_barrier(0);                                        \
    __builtin_amdgcn_s_barrier();                                             \
    __builtin_amdgcn_sched_barrier(0);                                        \
    const float* sb = &Abuf[s & 7][0];                                        \
    const int r0 = q * 64;                                                    \
    f32x4 a00 = *(const f32x4*)(sb + r0 + (((2 * g)     ^ q) << 2));          \
    f32x4 a01 = *(const f32x4*)(sb + r0 + (((2 * g + 1) ^ q) << 2));          \
    f32x4 a10 = *(const f32x4*)(sb + r0 + (((2 * g + 8) ^ q) << 2));          \
    f32x4 a11 = *(const f32x4*)(sb + r0 + (((2 * g + 9) ^ q) << 2));          \
    u32x4 w0, w1;                                                             \
    w0[0] = cvtpk(a00[0], a00[1]); w0[1] = cvtpk(a00[2], a00[3]);             \
    w0[2] = cvtpk(a01[0], a01[1]); w0[3] = cvtpk(a01[2], a01[3]);             \
    w1[0] = cvtpk(a10[0], a10[1]); w1[1] = cvtpk(a10[2], a10[3]);             \
    w1[2] = cvtpk(a11[0], a11[1]); w1[3] = cvtpk(a11[2], a11[3]);             \
    acc = __builtin_amdgcn_mfma_f32_16x16x32_bf16(                            \
        __builtin_bit_cast(s16x8, w0), BRl, acc, 0, 0, 0);                    \
    acc = __builtin_amdgcn_mfma_f32_16x16x32_bf16(                            \
        __builtin_bit_cast(s16x8, w1), BRh, acc, 0, 0, 0);                    \
    ++s;                                                                      \
  } while (0)

  for (int it = 0; it < NSTEP / 3; ++it) {
    K2STEP(b2l, b2h, b0l, b0h);  // read B(s), prefetch B(s+2)
    K2STEP(b0l, b0h, b1l, b1h);
    K2STEP(b1l, b1h, b2l, b2h);
  }
#undef K2STEP
#undef GLL

  // drain overrun glls before s_endpgm (LDS may be re-assigned to next block)
  asm volatile("s_waitcnt vmcnt(0)" ::: "memory");

  // epilogue: add self-term, relu, direct store
  const int c = w * 16 + q;
#pragma unroll
  for (int rr = 0; rr < 4; ++rr) {
    int i = i0 + g * 4 + rr;
    size_t idx = ((size_t)(b * NDIM) + i) * CDIM + c;
    float v = acc[rr] + S[idx];
    out[idx] = v > 0.f ? v : 0.f;
  }
}

extern "C" void kernel_launch(void* const* d_in, const int* in_sizes, int n_in,
                              void* d_out, int out_size, void* d_ws, size_t ws_size,
                              hipStream_t stream) {
  const float* V  = (const float*)d_in[0];
  const float* A  = (const float*)d_in[1];
  const float* hw = (const float*)d_in[2];
  float* out = (float*)d_out;

  float* S = (float*)d_ws;
  unsigned short* Ut =
      (unsigned short*)((char*)d_ws + (size_t)BDIM * NDIM * CDIM * sizeof(float));

  k1_precompute<<<dim3(NDIM / 16, LDIM + 1, BDIM), 64, 0, stream>>>(V, hw, S, Ut);
  k2_main<<<dim3((NDIM / 16) * BDIM), 256, 0, stream>>>(A, Ut, S, out);
}

// Round 6
// 47.973 us; speedup vs baseline: 1.7699x; 1.3687x over previous
//
#include <hip/hip_runtime.h>
#include <cstdint>

#define BDIM 4
#define NDIM 2048
#define FDIM 64
#define CDIM 64
#define LDIM 3
#define KTOT (NDIM * LDIM)   /* 6144 */
#define BK 256
#define NSTEP (KTOT / BK)    /* 24 */
#define KB (KTOT / 32)       /* 192 */

typedef __attribute__((ext_vector_type(4))) float f32x4;
typedef __attribute__((ext_vector_type(8))) short s16x8;
typedef __attribute__((ext_vector_type(4))) unsigned int u32x4;

__device__ __forceinline__ unsigned short f2bf(float x) {
  union { float f; uint32_t u; } v; v.f = x;
  uint32_t r = v.u + 0x7FFFu + ((v.u >> 16) & 1u);
  return (unsigned short)(r >> 16);
}

__device__ __forceinline__ uint32_t cvtpk(float lo, float hi) {
  uint32_t r;
  asm("v_cvt_pk_bf16_f32 %0, %1, %2" : "=v"(r) : "v"(lo), "v"(hi));
  return r;
}

// ---------------------------------------------------------------------------
// K1: S[b,i,c] = sum_f h0[c,f] V[b,i,f]   (fp32, ws)
//     Ut3[b][kb][cw][g][q][e] = U[b][c=cw*16+q][k=kb*32+g*8+e]  (bf16, ws)
//     where U[b][c][k=j*3+l] = sum_f h_{1+l}[c,f] V[b,j,f].
// Layout chosen so k2's B-load per wave is 1 KB fully contiguous.
// MFMA 16x16x32 lane maps (verified R1-R5, absmax 0.5):
//   A: row=l&15, k=(l>>4)*8+e ; B: col=l&15, same k ; D: col=l&15, row=(l>>4)*4+rr
// ---------------------------------------------------------------------------
__global__ __launch_bounds__(64) void k1_precompute(
    const float* __restrict__ V, const float* __restrict__ hw,
    float* __restrict__ S, unsigned short* __restrict__ Ut3) {
  const int j0 = blockIdx.x * 16;
  const int le = blockIdx.y;
  const int b  = blockIdx.z;
  const int lane = threadIdx.x;
  const int q = lane & 15, g = lane >> 4;

  const float* vrow = V + ((size_t)(b * NDIM + j0 + q)) * FDIM + g * 8;
  f32x4 va0 = *(const f32x4*)(vrow);
  f32x4 va1 = *(const f32x4*)(vrow + 4);
  f32x4 va2 = *(const f32x4*)(vrow + 32);
  f32x4 va3 = *(const f32x4*)(vrow + 36);
  s16x8 a0, a1;
#pragma unroll
  for (int e = 0; e < 4; ++e) {
    a0[e]     = (short)f2bf(va0[e]);
    a0[e + 4] = (short)f2bf(va1[e]);
    a1[e]     = (short)f2bf(va2[e]);
    a1[e + 4] = (short)f2bf(va3[e]);
  }

  const float* hbase = hw + (size_t)le * CDIM * FDIM;
#pragma unroll
  for (int ct = 0; ct < 4; ++ct) {
    const float* hrow = hbase + (size_t)(ct * 16 + q) * FDIM + g * 8;
    f32x4 hb0 = *(const f32x4*)(hrow);
    f32x4 hb1 = *(const f32x4*)(hrow + 4);
    f32x4 hb2 = *(const f32x4*)(hrow + 32);
    f32x4 hb3 = *(const f32x4*)(hrow + 36);
    s16x8 b0, b1;
#pragma unroll
    for (int e = 0; e < 4; ++e) {
      b0[e]     = (short)f2bf(hb0[e]);
      b0[e + 4] = (short)f2bf(hb1[e]);
      b1[e]     = (short)f2bf(hb2[e]);
      b1[e + 4] = (short)f2bf(hb3[e]);
    }
    f32x4 acc = {0.f, 0.f, 0.f, 0.f};
    acc = __builtin_amdgcn_mfma_f32_16x16x32_bf16(a0, b0, acc, 0, 0, 0);
    acc = __builtin_amdgcn_mfma_f32_16x16x32_bf16(a1, b1, acc, 0, 0, 0);
    if (le == 0) {
#pragma unroll
      for (int rr = 0; rr < 4; ++rr) {
        int j = j0 + g * 4 + rr;
        S[((size_t)b * NDIM + j) * CDIM + ct * 16 + q] = acc[rr];
      }
    } else {
#pragma unroll
      for (int rr = 0; rr < 4; ++rr) {
        int j = j0 + g * 4 + rr;
        int k = j * 3 + (le - 1);
        int kb = k >> 5, gg = (k >> 3) & 3, ee = k & 7;
        size_t off = ((size_t)b * KB + kb) * 2048 + (size_t)ct * 512 +
                     (size_t)gg * 128 + (size_t)q * 8 + ee;
        Ut3[off] = f2bf(acc[rr]);
      }
    }
  }
}

// ---------------------------------------------------------------------------
// K2: out[b, i0..i0+15, :] = relu(S + A[b,i0:i0+16,:] @ U[b])
// M=16, BK=256/step, 24 steps, 4 waves (wave w -> cols w*16..+15), full K.
// Grid 512 = 2 blocks/CU. Every VMEM instruction reads 1 KB contiguous:
//   A: wave w stages rows 4w..4w+3, one GLL = one row-KB; 16B granules
//      XOR-preswizzled by row&7 at the SOURCE (LDS dest linear, rule #21);
//      ds_read applies the same XOR -> 2 lanes/bank (free).
//   B: Ut3 layout makes each wave's per-kb load base + lane*16B contiguous.
// Ring 4 x 16KB slots, GLL issue-ahead 2 slots; B prefetch 1 step.
// Per region 12 vmem ops (4 GLL + 8 B) -> counted vmcnt(12); NEVER 0 in loop.
// ---------------------------------------------------------------------------
__global__ __launch_bounds__(256) void k2_main(
    const float* __restrict__ A, const unsigned short* __restrict__ Ut3,
    const float* __restrict__ S, float* __restrict__ out) {
  __shared__ float Abuf[4][4096];  // 4 slots x 16 rows x 256 floats = 64 KB

  const int bid = blockIdx.x;
  const int swz = (bid & 7) * 64 + (bid >> 3);  // XCD-chunked, 512 % 8 == 0
  const int b   = swz >> 7;
  const int i0  = (swz & 127) * 16;
  const int tid = threadIdx.x;
  const int lane = tid & 63, w = tid >> 6;
  const int q = lane & 15, g = lane >> 4, q7 = q & 7;

  // A sources: wave w stages rows 4w..4w+3, 1 KB contiguous per GLL
  const int r0 = 4 * w;
  const float* ag0 = A + ((size_t)(b * NDIM + i0 + r0 + 0)) * KTOT + ((lane ^ ((r0 + 0) & 7)) * 4);
  const float* ag1 = A + ((size_t)(b * NDIM + i0 + r0 + 1)) * KTOT + ((lane ^ ((r0 + 1) & 7)) * 4);
  const float* ag2 = A + ((size_t)(b * NDIM + i0 + r0 + 2)) * KTOT + ((lane ^ ((r0 + 2) & 7)) * 4);
  const float* ag3 = A + ((size_t)(b * NDIM + i0 + r0 + 3)) * KTOT + ((lane ^ ((r0 + 3) & 7)) * 4);

  // B source: per step 8 x 1 KB contiguous (kb = s*8+t), lane offset lane*16B
  const unsigned short* bgp = Ut3 + (size_t)b * KB * 2048 + w * 512 + lane * 8;

  // LDS dest: wave-uniform base + lane*16B (GLL requirement)
  float* ldsw = &Abuf[0][0] + r0 * 256 + lane * 4;

#define GLL4(slot)                                                            \
  do {                                                                        \
    __builtin_amdgcn_global_load_lds(                                         \
        (__attribute__((address_space(1))) void*)(ag0),                       \
        (__attribute__((address_space(3))) void*)(ldsw + (slot) * 4096), 16, 0, 0); \
    __builtin_amdgcn_global_load_lds(                                         \
        (__attribute__((address_space(1))) void*)(ag1),                       \
        (__attribute__((address_space(3))) void*)(ldsw + (slot) * 4096 + 256), 16, 0, 0); \
    __builtin_amdgcn_global_load_lds(                                         \
        (__attribute__((address_space(1))) void*)(ag2),                       \
        (__attribute__((address_space(3))) void*)(ldsw + (slot) * 4096 + 512), 16, 0, 0); \
    __builtin_amdgcn_global_load_lds(                                         \
        (__attribute__((address_space(1))) void*)(ag3),                       \
        (__attribute__((address_space(3))) void*)(ldsw + (slot) * 4096 + 768), 16, 0, 0); \
  } while (0)

#define LDB(BW)                                                               \
  do {                                                                        \
    _Pragma("unroll")                                                         \
    for (int t = 0; t < 8; ++t)                                               \
      BW[t] = *(const s16x8*)(bgp + (size_t)t * 2048);                        \
  } while (0)

  f32x4 accA = {0.f, 0.f, 0.f, 0.f}, accB = {0.f, 0.f, 0.f, 0.f};
  s16x8 bA[8], bB[8];

  // prologue: [GLL(0)x4, GLL(1)x4, B(0)x8] = 16 vmem ops
  GLL4(0); ag0 += BK; ag1 += BK; ag2 += BK; ag3 += BK;
  GLL4(1); ag0 += BK; ag1 += BK; ag2 += BK; ag3 += BK;
  LDB(bA); bgp += 8 * 2048;

  int s = 0;
  // region s issues {GLL(s+2)x4, B(s+1)x8}; vmcnt(12) => A(s) in LDS, B(s)
  // in regs (region-level membership, robust to intra-region reorder).
  // GLL(s+2) overwrites slot (s+2)&3, last read at step s-2 whose readers
  // passed barrier s-1 => race-free with one barrier per step.
#define K2STEP(BW, BR)                                                        \
  do {                                                                        \
    GLL4((s + 2) & 3);                                                        \
    if (s + 2 < NSTEP - 1) { ag0 += BK; ag1 += BK; ag2 += BK; ag3 += BK; }    \
    LDB(BW);                                                                  \
    if (s + 2 < NSTEP) bgp += 8 * 2048;                                       \
    asm volatile("s_waitcnt vmcnt(12)" ::: "memory");                         \
    __builtin_amdgcn_sched_barrier(0);                                        \
    __builtin_amdgcn_s_barrier();                                             \
    __builtin_amdgcn_sched_barrier(0);                                        \
    const float* rowp = &Abuf[s & 3][0] + q * 256;                            \
    _Pragma("unroll")                                                         \
    for (int kk = 0; kk < 8; ++kk) {                                          \
      f32x4 a0 = *(const f32x4*)(rowp + ((kk * 8 + ((2 * g) ^ q7)) << 2));    \
      f32x4 a1 = *(const f32x4*)(rowp + ((kk * 8 + ((2 * g + 1) ^ q7)) << 2));\
      u32x4 wv;                                                               \
      wv[0] = cvtpk(a0[0], a0[1]); wv[1] = cvtpk(a0[2], a0[3]);               \
      wv[2] = cvtpk(a1[0], a1[1]); wv[3] = cvtpk(a1[2], a1[3]);               \
      if (kk & 1)                                                             \
        accB = __builtin_amdgcn_mfma_f32_16x16x32_bf16(                       \
            __builtin_bit_cast(s16x8, wv), BR[kk], accB, 0, 0, 0);            \
      else                                                                    \
        accA = __builtin_amdgcn_mfma_f32_16x16x32_bf16(                       \
            __builtin_bit_cast(s16x8, wv), BR[kk], accA, 0, 0, 0);            \
    }                                                                         \
    ++s;                                                                      \
  } while (0)

  for (int it = 0; it < NSTEP / 2; ++it) {
    K2STEP(bB, bA);  // consume B(s)=bA, prefetch B(s+1) into bB
    K2STEP(bA, bB);
  }
#undef K2STEP
#undef GLL4
#undef LDB

  // drain overrun glls before s_endpgm (LDS may be re-assigned)
  asm volatile("s_waitcnt vmcnt(0)" ::: "memory");

  // epilogue: add self-term, relu, direct store
  f32x4 acc = accA + accB;
  const int c = w * 16 + q;
#pragma unroll
  for (int rr = 0; rr < 4; ++rr) {
    int i = i0 + g * 4 + rr;
    size_t idx = ((size_t)(b * NDIM) + i) * CDIM + c;
    float v = acc[rr] + S[idx];
    out[idx] = v > 0.f ? v : 0.f;
  }
}

extern "C" void kernel_launch(void* const* d_in, const int* in_sizes, int n_in,
                              void* d_out, int out_size, void* d_ws, size_t ws_size,
                              hipStream_t stream) {
  const float* V  = (const float*)d_in[0];
  const float* A  = (const float*)d_in[1];
  const float* hw = (const float*)d_in[2];
  float* out = (float*)d_out;

  float* S = (float*)d_ws;
  unsigned short* Ut3 =
      (unsigned short*)((char*)d_ws + (size_t)BDIM * NDIM * CDIM * sizeof(float));

  k1_precompute<<<dim3(NDIM / 16, LDIM + 1, BDIM), 64, 0, stream>>>(V, hw, S, Ut3);
  k2_main<<<dim3((NDIM / 16) * BDIM), 256, 0, stream>>>(A, Ut3, S, out);
}